// Round 2
// baseline (2455.665 us; speedup 1.0000x reference)
//
#include <hip/hip_runtime.h>

#define N_NODES   50000
#define N_EDGES   1600000
#define DDIM      64
#define N_GRAPHS  512
#define N_CLASSES 53
#define ITERS     3
#define NB        782            // ceil(N_NODES/64) buckets of 64 dst nodes
#define NPB       128            // partition blocks
#define CHUNK     ((N_EDGES + NPB - 1) / NPB)

__device__ __forceinline__ float bcast_lane(float v, int l) {
  return __uint_as_float(__builtin_amdgcn_readlane(__float_as_uint(v), l));
}
__device__ __forceinline__ unsigned rdlane_u(unsigned v, int l) {
  return (unsigned)__builtin_amdgcn_readlane((int)v, l);
}

// h[node][d] = emb[pkt[node]][d], float4-vectorized
__global__ void embed_kernel(const int* __restrict__ pkt, const float4* __restrict__ emb,
                             float4* __restrict__ h) {
  int idx = blockIdx.x * 256 + threadIdx.x;
  if (idx >= N_NODES * 16) return;
  int node = idx >> 4;
  h[idx] = emb[(size_t)pkt[node] * 16 + (idx & 15)];
}

// edge-count per 64-node dst bucket, LDS-staged
__global__ void bucket_hist_kernel(const int* __restrict__ dst, int* __restrict__ bhist) {
  __shared__ int lh[NB];
  for (int i = threadIdx.x; i < NB; i += 256) lh[i] = 0;
  __syncthreads();
  int stride = gridDim.x * 256;
  for (int e = blockIdx.x * 256 + threadIdx.x; e < N_EDGES; e += stride)
    atomicAdd(&lh[dst[e] >> 6], 1);
  __syncthreads();
  for (int i = threadIdx.x; i < NB; i += 256)
    if (lh[i]) atomicAdd(&bhist[i], lh[i]);
}

__global__ void hist_kernel(const int* __restrict__ idx, int* __restrict__ counts, int n) {
  int i = blockIdx.x * 256 + threadIdx.x;
  if (i < n) atomicAdd(&counts[idx[i]], 1);
}

// single-block exclusive scan (n <= 1024 per pass handled by the loop); offs[n] = total
__global__ void scan_kernel(const int* __restrict__ counts, int* __restrict__ offs,
                            int* __restrict__ cursor, int n) {
  __shared__ int wsum[16];
  __shared__ int carry;
  int tid = threadIdx.x;               // 1024 threads
  if (tid == 0) carry = 0;
  __syncthreads();
  for (int base = 0; base < n; base += 1024) {
    int i = base + tid;
    int v = (i < n) ? counts[i] : 0;
    int x = v;
    #pragma unroll
    for (int off = 1; off < 64; off <<= 1) {
      int y = __shfl_up(x, off);
      if ((tid & 63) >= off) x += y;
    }
    int w = tid >> 6;
    if ((tid & 63) == 63) wsum[w] = x;
    __syncthreads();
    int woff = 0;
    for (int k = 0; k < w; ++k) woff += wsum[k];
    int incl = x + woff + carry;
    if (i < n) {
      offs[i] = incl - v;
      if (cursor) cursor[i] = incl - v;
    }
    __syncthreads();
    if (tid == 1023) carry = incl;
    __syncthreads();
  }
  if (tid == 0) offs[n] = carry;
}

// bucket-partition edges: ebuf[pos] = src(16b) | (dst&63)<<16, grouped by dst>>6
__global__ void partition_kernel(const int* __restrict__ src, const int* __restrict__ dst,
                                 int* __restrict__ bcursor, unsigned* __restrict__ ebuf) {
  __shared__ int lh[NB];
  __shared__ int lbase[NB];
  for (int i = threadIdx.x; i < NB; i += 256) lh[i] = 0;
  __syncthreads();
  int e0 = blockIdx.x * CHUNK;
  int e1 = min(e0 + CHUNK, N_EDGES);
  for (int e = e0 + (int)threadIdx.x; e < e1; e += 256)
    atomicAdd(&lh[dst[e] >> 6], 1);
  __syncthreads();
  for (int i = threadIdx.x; i < NB; i += 256) {
    int c = lh[i];
    lbase[i] = c ? atomicAdd(&bcursor[i], c) : 0;
    lh[i] = 0;                         // reuse as running cursor
  }
  __syncthreads();
  for (int e = e0 + (int)threadIdx.x; e < e1; e += 256) {
    int d = dst[e];
    int b = d >> 6;
    int pos = lbase[b] + atomicAdd(&lh[b], 1);
    ebuf[pos] = (unsigned)src[e] | ((unsigned)(d & 63) << 16);
  }
}

// block = one 64-node bucket; 64x64 f32 accumulator in LDS; lane = feature
__global__ __launch_bounds__(256) void bucket_agg_kernel(
    const float* __restrict__ h, const int* __restrict__ boffs,
    const unsigned* __restrict__ ebuf, const float* __restrict__ epsp,
    float* __restrict__ x) {
  __shared__ float acc[64 * 64];       // 16 KB
  const int tid = threadIdx.x, lane = tid & 63, wave = tid >> 6;
  for (int i = tid; i < 64 * 64; i += 256) acc[i] = 0.f;
  __syncthreads();
  const int b = blockIdx.x;
  const int ebeg = boffs[b], eend = boffs[b + 1];
  for (int base = ebeg + wave * 64; base < eend; base += 256) {
    int cnt = min(64, eend - base);
    unsigned pk = 0;
    if (lane < cnt) pk = ebuf[base + lane];
    int k = 0;
    for (; k + 4 <= cnt; k += 4) {     // 4 gathers in flight per wave
      unsigned p0 = rdlane_u(pk, k + 0);
      unsigned p1 = rdlane_u(pk, k + 1);
      unsigned p2 = rdlane_u(pk, k + 2);
      unsigned p3 = rdlane_u(pk, k + 3);
      float a0 = h[(size_t)(p0 & 0xFFFFu) * DDIM + lane];
      float a1 = h[(size_t)(p1 & 0xFFFFu) * DDIM + lane];
      float a2 = h[(size_t)(p2 & 0xFFFFu) * DDIM + lane];
      float a3 = h[(size_t)(p3 & 0xFFFFu) * DDIM + lane];
      atomicAdd(&acc[((p0 >> 16) & 63u) * 64 + lane], a0);
      atomicAdd(&acc[((p1 >> 16) & 63u) * 64 + lane], a1);
      atomicAdd(&acc[((p2 >> 16) & 63u) * 64 + lane], a2);
      atomicAdd(&acc[((p3 >> 16) & 63u) * 64 + lane], a3);
    }
    for (; k < cnt; ++k) {
      unsigned p = rdlane_u(pk, k);
      float a = h[(size_t)(p & 0xFFFFu) * DDIM + lane];
      atomicAdd(&acc[((p >> 16) & 63u) * 64 + lane], a);
    }
  }
  __syncthreads();
  const float ep = 1.0f + epsp[0];
  for (int r = wave; r < 64; r += 4) {
    int node = b * 64 + r;
    if (node < N_NODES)
      x[(size_t)node * DDIM + lane] =
          fmaf(ep, h[(size_t)node * DDIM + lane], acc[r * 64 + lane]);
  }
}

// one 64x64 Linear+ReLU with weight column resident in 64 VGPRs (static-indexed)
#define LAYER(v, w, bias, outv)                                     \
  {                                                                 \
    float y0 = (bias), y1 = 0.f, y2 = 0.f, y3 = 0.f;                \
    _Pragma("unroll")                                               \
    for (int d = 0; d < 64; d += 4) {                               \
      y0 = fmaf(bcast_lane(v, d + 0), w[d + 0], y0);                \
      y1 = fmaf(bcast_lane(v, d + 1), w[d + 1], y1);                \
      y2 = fmaf(bcast_lane(v, d + 2), w[d + 2], y2);                \
      y3 = fmaf(bcast_lane(v, d + 3), w[d + 3], y3);                \
    }                                                               \
    outv = fmaxf((y0 + y1) + (y2 + y3), 0.f);                       \
  }

__global__ __launch_bounds__(256) void mlp_kernel(
    const float* __restrict__ xin, float* __restrict__ xout,
    const float* __restrict__ W1, const float* __restrict__ b1,
    const float* __restrict__ W2, const float* __restrict__ b2,
    const float* __restrict__ W3, const float* __restrict__ b3,
    float* __restrict__ bnsum, float* __restrict__ bnsq) {
  const int lane = threadIdx.x & 63;
  const int wave = blockIdx.x * 4 + (threadIdx.x >> 6);
  const int nwaves = gridDim.x * 4;
  float w1[64], w2[64], w3[64];
  #pragma unroll
  for (int d = 0; d < 64; ++d) {
    w1[d] = W1[d * 64 + lane];
    w2[d] = W2[d * 64 + lane];
    w3[d] = W3[d * 64 + lane];
  }
  const float bb1 = b1[lane], bb2 = b2[lane], bb3 = b3[lane];
  float s = 0.f, sq = 0.f;
  for (int row = wave; row < N_NODES; row += nwaves) {
    float v = xin[(size_t)row * DDIM + lane];
    float t;
    LAYER(v, w1, bb1, t); v = t;
    LAYER(v, w2, bb2, t); v = t;
    LAYER(v, w3, bb3, t); v = t;
    xout[(size_t)row * DDIM + lane] = v;
    s += v;
    sq += v * v;
  }
  atomicAdd(&bnsum[lane], s);
  atomicAdd(&bnsq[lane], sq);
}

__global__ void bn_finalize_kernel(float* __restrict__ bnsum, float* __restrict__ bnsq,
                                   float* __restrict__ stats) {
  int lane = threadIdx.x;              // 64 threads
  const float invN = 1.0f / N_NODES;
  float m = bnsum[lane] * invN;
  float var = bnsq[lane] * invN - m * m;
  stats[lane] = m;
  stats[64 + lane] = 1.0f / sqrtf(var + 1e-5f);
  bnsum[lane] = 0.f;
  bnsq[lane] = 0.f;
}

// BN-apply -> h, plus atomic-free graph pooling (block per graph; graph_ids sorted)
__global__ void norm_pool_kernel(const float* __restrict__ x, float* __restrict__ h,
                                 float* __restrict__ pooled, const int* __restrict__ goff,
                                 const float* __restrict__ stats, const float* __restrict__ gamma,
                                 const float* __restrict__ beta, int iter) {
  int g = blockIdx.x;
  int lane = threadIdx.x & 63;
  int wave = threadIdx.x >> 6;
  float mean = stats[lane];
  float inv = stats[64 + lane];
  float gm = gamma[lane] * inv;
  float bt = beta[lane] - mean * gm;
  int rbeg = goff[g], rend = goff[g + 1];
  float acc = 0.f;
  for (int r = rbeg + wave; r < rend; r += 4) {
    float v = fmaf(x[(size_t)r * DDIM + lane], gm, bt);
    h[(size_t)r * DDIM + lane] = v;
    acc += v;
  }
  __shared__ float red[4][64];
  red[wave][lane] = acc;
  __syncthreads();
  if (wave == 0) {
    pooled[(size_t)g * (ITERS * DDIM) + iter * DDIM + lane] =
        red[0][lane] + red[1][lane] + red[2][lane] + red[3][lane];
  }
}

__global__ void classifier_kernel(const float* __restrict__ pooled, const float* __restrict__ Wc,
                                  const float* __restrict__ bc, float* __restrict__ out) {
  int g = blockIdx.x;
  int c = threadIdx.x;
  if (c >= N_CLASSES) return;
  float acc = bc[c];
  #pragma unroll 4
  for (int k = 0; k < ITERS * DDIM; ++k)
    acc = fmaf(pooled[(size_t)g * (ITERS * DDIM) + k], Wc[k * N_CLASSES + c], acc);
  out[(size_t)g * N_CLASSES + c] = acc;
}

extern "C" void kernel_launch(void* const* d_in, const int* in_sizes, int n_in,
                              void* d_out, int out_size, void* d_ws, size_t ws_size,
                              hipStream_t stream) {
  const int*   pkt   = (const int*)d_in[0];
  const int*   src   = (const int*)d_in[1];
  const int*   dst   = (const int*)d_in[2];
  const int*   gids  = (const int*)d_in[3];
  const float* emb   = (const float*)d_in[4];
  const float* eps   = (const float*)d_in[5];
  const float* W1    = (const float*)d_in[6];
  const float* b1    = (const float*)d_in[7];
  const float* W2    = (const float*)d_in[8];
  const float* b2    = (const float*)d_in[9];
  const float* W3    = (const float*)d_in[10];
  const float* b3    = (const float*)d_in[11];
  const float* gamma = (const float*)d_in[12];
  const float* beta  = (const float*)d_in[13];
  const float* Wc    = (const float*)d_in[14];
  const float* bc    = (const float*)d_in[15];
  float* out = (float*)d_out;

  char* p = (char*)d_ws;
  auto alloc = [&](size_t bytes) {
    char* r = p;
    p += (bytes + 255) & ~(size_t)255;
    return r;
  };
  float*    h       = (float*)alloc((size_t)N_NODES * DDIM * 4);
  float*    x       = (float*)alloc((size_t)N_NODES * DDIM * 4);
  unsigned* ebuf    = (unsigned*)alloc((size_t)N_EDGES * 4);
  int*      boffs   = (int*)alloc((size_t)(NB + 1) * 4);
  int*      bcursor = (int*)alloc((size_t)NB * 4);
  int*      goff    = (int*)alloc((size_t)(N_GRAPHS + 1) * 4);
  float*    pooled  = (float*)alloc((size_t)N_GRAPHS * ITERS * DDIM * 4);
  float*    stats   = (float*)alloc(128 * 4);
  // contiguous zero region: bhist | gcnt | bnsum | bnsq
  size_t zbytes = (size_t)NB * 4 + (size_t)N_GRAPHS * 4 + 512;
  char*  zbase  = alloc(zbytes);
  int*   bhist  = (int*)zbase;
  int*   gcnt   = bhist + NB;
  float* bnsum  = (float*)(gcnt + N_GRAPHS);
  float* bnsq   = bnsum + 64;

  hipMemsetAsync(zbase, 0, zbytes, stream);

  embed_kernel<<<(N_NODES * 16 + 255) / 256, 256, 0, stream>>>(pkt, (const float4*)emb,
                                                               (float4*)h);
  bucket_hist_kernel<<<256, 256, 0, stream>>>(dst, bhist);
  hist_kernel<<<(N_NODES + 255) / 256, 256, 0, stream>>>(gids, gcnt, N_NODES);
  scan_kernel<<<1, 1024, 0, stream>>>(bhist, boffs, bcursor, NB);
  scan_kernel<<<1, 1024, 0, stream>>>(gcnt, goff, nullptr, N_GRAPHS);
  partition_kernel<<<NPB, 256, 0, stream>>>(src, dst, bcursor, ebuf);

  for (int it = 0; it < ITERS; ++it) {
    bucket_agg_kernel<<<NB, 256, 0, stream>>>(h, boffs, ebuf, eps, x);
    mlp_kernel<<<512, 256, 0, stream>>>(x, x, W1, b1, W2, b2, W3, b3, bnsum, bnsq);
    bn_finalize_kernel<<<1, 64, 0, stream>>>(bnsum, bnsq, stats);
    norm_pool_kernel<<<N_GRAPHS, 256, 0, stream>>>(x, h, pooled, goff, stats, gamma, beta, it);
  }
  classifier_kernel<<<N_GRAPHS, 64, 0, stream>>>(pooled, Wc, bc, out);
}

// Round 3
// 604.898 us; speedup vs baseline: 4.0596x; 4.0596x over previous
//
#include <hip/hip_runtime.h>

#define N_NODES   50000
#define N_EDGES   1600000
#define DDIM      64
#define N_GRAPHS  512
#define N_CLASSES 53
#define ITERS     3
#define NB        782            // ceil(N_NODES/64) buckets of 64 dst nodes
#define NPB       128            // partition blocks
#define CHUNK     ((N_EDGES + NPB - 1) / NPB)

__device__ __forceinline__ float bcast_lane(float v, int l) {
  return __uint_as_float(__builtin_amdgcn_readlane(__float_as_uint(v), l));
}

// h[node][d] = emb[pkt[node]][d], float4-vectorized
__global__ void embed_kernel(const int* __restrict__ pkt, const float4* __restrict__ emb,
                             float4* __restrict__ h) {
  int idx = blockIdx.x * 256 + threadIdx.x;
  if (idx >= N_NODES * 16) return;
  int node = idx >> 4;
  h[idx] = emb[(size_t)pkt[node] * 16 + (idx & 15)];
}

// edge-count per 64-node dst bucket, LDS-staged
__global__ void bucket_hist_kernel(const int* __restrict__ dst, int* __restrict__ bhist) {
  __shared__ int lh[NB];
  for (int i = threadIdx.x; i < NB; i += 256) lh[i] = 0;
  __syncthreads();
  int stride = gridDim.x * 256;
  for (int e = blockIdx.x * 256 + threadIdx.x; e < N_EDGES; e += stride)
    atomicAdd(&lh[dst[e] >> 6], 1);
  __syncthreads();
  for (int i = threadIdx.x; i < NB; i += 256)
    if (lh[i]) atomicAdd(&bhist[i], lh[i]);
}

__global__ void hist_kernel(const int* __restrict__ idx, int* __restrict__ counts, int n) {
  int i = blockIdx.x * 256 + threadIdx.x;
  if (i < n) atomicAdd(&counts[idx[i]], 1);
}

// single-block exclusive scan; offs[n] = total; optional cursor copy (n <= 1024 here)
__global__ void scan_kernel(const int* __restrict__ counts, int* __restrict__ offs,
                            int* __restrict__ cursor, int n) {
  __shared__ int wsum[16];
  __shared__ int carry;
  int tid = threadIdx.x;               // 1024 threads
  if (tid == 0) carry = 0;
  __syncthreads();
  for (int base = 0; base < n; base += 1024) {
    int i = base + tid;
    int v = (i < n) ? counts[i] : 0;
    int x = v;
    #pragma unroll
    for (int off = 1; off < 64; off <<= 1) {
      int y = __shfl_up(x, off);
      if ((tid & 63) >= off) x += y;
    }
    int w = tid >> 6;
    if ((tid & 63) == 63) wsum[w] = x;
    __syncthreads();
    int woff = 0;
    for (int k = 0; k < w; ++k) woff += wsum[k];
    int incl = x + woff + carry;
    if (i < n) {
      offs[i] = incl - v;
      if (cursor) cursor[i] = incl - v;
    }
    __syncthreads();
    if (tid == 1023) carry = incl;
    __syncthreads();
  }
  if (tid == 0) offs[n] = carry;
}

// bucket-partition edges: ebuf[pos] = src(16b) | (dst&63)<<16, grouped by dst>>6
__global__ void partition_kernel(const int* __restrict__ src, const int* __restrict__ dst,
                                 int* __restrict__ bcursor, unsigned* __restrict__ ebuf) {
  __shared__ int lh[NB];
  __shared__ int lbase[NB];
  for (int i = threadIdx.x; i < NB; i += 256) lh[i] = 0;
  __syncthreads();
  int e0 = blockIdx.x * CHUNK;
  int e1 = min(e0 + CHUNK, N_EDGES);
  for (int e = e0 + (int)threadIdx.x; e < e1; e += 256)
    atomicAdd(&lh[dst[e] >> 6], 1);
  __syncthreads();
  for (int i = threadIdx.x; i < NB; i += 256) {
    int c = lh[i];
    lbase[i] = c ? atomicAdd(&bcursor[i], c) : 0;
    lh[i] = 0;                         // reuse as running cursor
  }
  __syncthreads();
  for (int e = e0 + (int)threadIdx.x; e < e1; e += 256) {
    int d = dst[e];
    int b = d >> 6;
    int pos = lbase[b] + atomicAdd(&lh[b], 1);
    ebuf[pos] = (unsigned)src[e] | ((unsigned)(d & 63) << 16);
  }
}

// block per bucket: per-node offsets (in-block 64-scan) + CSR scatter into an
// ~8KB contiguous window (sequential reads, local writes -> no amplification)
__global__ __launch_bounds__(256) void local_scatter_kernel(
    const unsigned* __restrict__ ebuf, const int* __restrict__ boffs,
    int* __restrict__ offs, int* __restrict__ csr) {
  __shared__ int cnt[64];
  __shared__ int base[64];
  const int b = blockIdx.x;
  const int tid = threadIdx.x;
  if (tid < 64) cnt[tid] = 0;
  __syncthreads();
  const int ebeg = boffs[b], eend = boffs[b + 1];
  for (int e = ebeg + tid; e < eend; e += 256)
    atomicAdd(&cnt[(ebuf[e] >> 16) & 63u], 1);
  __syncthreads();
  if (tid < 64) {                      // wave 0: exclusive scan of 64 counts
    int v = cnt[tid];
    int x = v;
    #pragma unroll
    for (int off = 1; off < 64; off <<= 1) {
      int y = __shfl_up(x, off);
      if (tid >= off) x += y;
    }
    int excl = ebeg + x - v;
    base[tid] = excl;
    int node = b * 64 + tid;
    if (node < N_NODES) offs[node] = excl;
    cnt[tid] = 0;                      // reuse as running cursor
  }
  __syncthreads();
  for (int e = ebeg + tid; e < eend; e += 256) {
    unsigned p = ebuf[e];
    int j = (p >> 16) & 63u;
    int pos = base[j] + atomicAdd(&cnt[j], 1);
    csr[pos] = (int)(p & 0xFFFFu);
  }
  if (b == NB - 1 && tid == 0) offs[N_NODES] = N_EDGES;
}

// x[v] = (1+eps)*h[v] + sum_{u in in-nbrs(v)} h[u]; wave per node, lane = feature
__global__ void aggregate_kernel(const float* __restrict__ h, const int* __restrict__ offs,
                                 const int* __restrict__ csr, const float* __restrict__ epsp,
                                 float* __restrict__ x) {
  int node = blockIdx.x * 4 + (threadIdx.x >> 6);
  if (node >= N_NODES) return;
  int lane = threadIdx.x & 63;
  int beg = offs[node], end = offs[node + 1];
  float acc = (1.0f + epsp[0]) * h[(size_t)node * DDIM + lane];
  int e = beg;
  for (; e + 8 <= end; e += 8) {       // 8 gathers in flight (latency-bound)
    int u[8];
    #pragma unroll
    for (int q = 0; q < 8; ++q) u[q] = csr[e + q];
    float a[8];
    #pragma unroll
    for (int q = 0; q < 8; ++q) a[q] = h[(size_t)u[q] * DDIM + lane];
    acc += ((a[0] + a[1]) + (a[2] + a[3])) + ((a[4] + a[5]) + (a[6] + a[7]));
  }
  for (; e < end; ++e) acc += h[(size_t)csr[e] * DDIM + lane];
  x[(size_t)node * DDIM + lane] = acc;
}

// one 64x64 Linear+ReLU with weight column resident in 64 VGPRs (static-indexed)
#define LAYER(v, w, bias, outv)                                     \
  {                                                                 \
    float y0 = (bias), y1 = 0.f, y2 = 0.f, y3 = 0.f;                \
    _Pragma("unroll")                                               \
    for (int d = 0; d < 64; d += 4) {                               \
      y0 = fmaf(bcast_lane(v, d + 0), w[d + 0], y0);                \
      y1 = fmaf(bcast_lane(v, d + 1), w[d + 1], y1);                \
      y2 = fmaf(bcast_lane(v, d + 2), w[d + 2], y2);                \
      y3 = fmaf(bcast_lane(v, d + 3), w[d + 3], y3);                \
    }                                                               \
    outv = fmaxf((y0 + y1) + (y2 + y3), 0.f);                       \
  }

__global__ __launch_bounds__(256) void mlp_kernel(
    const float* __restrict__ xin, float* __restrict__ xout,
    const float* __restrict__ W1, const float* __restrict__ b1,
    const float* __restrict__ W2, const float* __restrict__ b2,
    const float* __restrict__ W3, const float* __restrict__ b3,
    float* __restrict__ bnsum, float* __restrict__ bnsq) {
  const int lane = threadIdx.x & 63;
  const int wave = blockIdx.x * 4 + (threadIdx.x >> 6);
  const int nwaves = gridDim.x * 4;
  float w1[64], w2[64], w3[64];        // weight columns resident in 192 VGPRs
  #pragma unroll
  for (int d = 0; d < 64; ++d) {
    w1[d] = W1[d * 64 + lane];
    w2[d] = W2[d * 64 + lane];
    w3[d] = W3[d * 64 + lane];
  }
  const float bb1 = b1[lane], bb2 = b2[lane], bb3 = b3[lane];
  float s = 0.f, sq = 0.f;
  for (int row = wave; row < N_NODES; row += nwaves) {
    float v = xin[(size_t)row * DDIM + lane];
    float t;
    LAYER(v, w1, bb1, t); v = t;
    LAYER(v, w2, bb2, t); v = t;
    LAYER(v, w3, bb3, t); v = t;
    xout[(size_t)row * DDIM + lane] = v;
    s += v;
    sq += v * v;
  }
  atomicAdd(&bnsum[lane], s);
  atomicAdd(&bnsq[lane], sq);
}

__global__ void bn_finalize_kernel(float* __restrict__ bnsum, float* __restrict__ bnsq,
                                   float* __restrict__ stats) {
  int lane = threadIdx.x;              // 64 threads
  const float invN = 1.0f / N_NODES;
  float m = bnsum[lane] * invN;
  float var = bnsq[lane] * invN - m * m;
  stats[lane] = m;
  stats[64 + lane] = 1.0f / sqrtf(var + 1e-5f);
  bnsum[lane] = 0.f;                   // ready for next iteration
  bnsq[lane] = 0.f;
}

// BN-apply -> h, plus atomic-free graph pooling (block per graph; graph_ids sorted)
__global__ void norm_pool_kernel(const float* __restrict__ x, float* __restrict__ h,
                                 float* __restrict__ pooled, const int* __restrict__ goff,
                                 const float* __restrict__ stats, const float* __restrict__ gamma,
                                 const float* __restrict__ beta, int iter) {
  int g = blockIdx.x;
  int lane = threadIdx.x & 63;
  int wave = threadIdx.x >> 6;
  float mean = stats[lane];
  float inv = stats[64 + lane];
  float gm = gamma[lane] * inv;
  float bt = beta[lane] - mean * gm;   // h = gm*v + bt
  int rbeg = goff[g], rend = goff[g + 1];
  float acc = 0.f;
  for (int r = rbeg + wave; r < rend; r += 4) {
    float v = fmaf(x[(size_t)r * DDIM + lane], gm, bt);
    h[(size_t)r * DDIM + lane] = v;
    acc += v;
  }
  __shared__ float red[4][64];
  red[wave][lane] = acc;
  __syncthreads();
  if (wave == 0) {
    pooled[(size_t)g * (ITERS * DDIM) + iter * DDIM + lane] =
        red[0][lane] + red[1][lane] + red[2][lane] + red[3][lane];
  }
}

__global__ void classifier_kernel(const float* __restrict__ pooled, const float* __restrict__ Wc,
                                  const float* __restrict__ bc, float* __restrict__ out) {
  int g = blockIdx.x;
  int c = threadIdx.x;
  if (c >= N_CLASSES) return;
  float acc = bc[c];
  #pragma unroll 4
  for (int k = 0; k < ITERS * DDIM; ++k)
    acc = fmaf(pooled[(size_t)g * (ITERS * DDIM) + k], Wc[k * N_CLASSES + c], acc);
  out[(size_t)g * N_CLASSES + c] = acc;
}

extern "C" void kernel_launch(void* const* d_in, const int* in_sizes, int n_in,
                              void* d_out, int out_size, void* d_ws, size_t ws_size,
                              hipStream_t stream) {
  const int*   pkt   = (const int*)d_in[0];
  const int*   src   = (const int*)d_in[1];
  const int*   dst   = (const int*)d_in[2];
  const int*   gids  = (const int*)d_in[3];
  const float* emb   = (const float*)d_in[4];
  const float* eps   = (const float*)d_in[5];
  const float* W1    = (const float*)d_in[6];
  const float* b1    = (const float*)d_in[7];
  const float* W2    = (const float*)d_in[8];
  const float* b2    = (const float*)d_in[9];
  const float* W3    = (const float*)d_in[10];
  const float* b3    = (const float*)d_in[11];
  const float* gamma = (const float*)d_in[12];
  const float* beta  = (const float*)d_in[13];
  const float* Wc    = (const float*)d_in[14];
  const float* bc    = (const float*)d_in[15];
  float* out = (float*)d_out;

  char* p = (char*)d_ws;
  auto alloc = [&](size_t bytes) {
    char* r = p;
    p += (bytes + 255) & ~(size_t)255;
    return r;
  };
  float*    h       = (float*)alloc((size_t)N_NODES * DDIM * 4);
  float*    x       = (float*)alloc((size_t)N_NODES * DDIM * 4);
  unsigned* ebuf    = (unsigned*)alloc((size_t)N_EDGES * 4);
  int*      csr     = (int*)alloc((size_t)N_EDGES * 4);
  int*      offs    = (int*)alloc((size_t)(N_NODES + 1) * 4);
  int*      boffs   = (int*)alloc((size_t)(NB + 1) * 4);
  int*      bcursor = (int*)alloc((size_t)NB * 4);
  int*      goff    = (int*)alloc((size_t)(N_GRAPHS + 1) * 4);
  float*    pooled  = (float*)alloc((size_t)N_GRAPHS * ITERS * DDIM * 4);
  float*    stats   = (float*)alloc(128 * 4);
  // contiguous zero region: bhist | gcnt | bnsum | bnsq
  size_t zbytes = (size_t)NB * 4 + (size_t)N_GRAPHS * 4 + 512;
  char*  zbase  = alloc(zbytes);
  int*   bhist  = (int*)zbase;
  int*   gcnt   = bhist + NB;
  float* bnsum  = (float*)(gcnt + N_GRAPHS);
  float* bnsq   = bnsum + 64;

  hipMemsetAsync(zbase, 0, zbytes, stream);

  embed_kernel<<<(N_NODES * 16 + 255) / 256, 256, 0, stream>>>(pkt, (const float4*)emb,
                                                               (float4*)h);
  bucket_hist_kernel<<<256, 256, 0, stream>>>(dst, bhist);
  hist_kernel<<<(N_NODES + 255) / 256, 256, 0, stream>>>(gids, gcnt, N_NODES);
  scan_kernel<<<1, 1024, 0, stream>>>(bhist, boffs, bcursor, NB);
  scan_kernel<<<1, 1024, 0, stream>>>(gcnt, goff, nullptr, N_GRAPHS);
  partition_kernel<<<NPB, 256, 0, stream>>>(src, dst, bcursor, ebuf);
  local_scatter_kernel<<<NB, 256, 0, stream>>>(ebuf, boffs, offs, csr);

  for (int it = 0; it < ITERS; ++it) {
    aggregate_kernel<<<(N_NODES + 3) / 4, 256, 0, stream>>>(h, offs, csr, eps, x);
    mlp_kernel<<<512, 256, 0, stream>>>(x, x, W1, b1, W2, b2, W3, b3, bnsum, bnsq);
    bn_finalize_kernel<<<1, 64, 0, stream>>>(bnsum, bnsq, stats);
    norm_pool_kernel<<<N_GRAPHS, 256, 0, stream>>>(x, h, pooled, goff, stats, gamma, beta, it);
  }
  classifier_kernel<<<N_GRAPHS, 64, 0, stream>>>(pooled, Wc, bc, out);
}